// Round 5
// baseline (66.898 us; speedup 1.0000x reference)
//
#include <hip/hip_runtime.h>

#define BB 1024
#define DD 512
#define OO 256

// ===========================================================================
// kA: all-independent roles in one launch:
//   P  (512 blocks): part[s][d][o] = sum_{b in slab s} max(x[b,d], t[b,o])
//   T  (512 blocks): transpose x -> xT[d][b]
//   Tt (256 blocks): transpose t -> tT[o][b]
//   W  (128 blocks): transpose w -> wT[o][d]
//   S  ( 16 blocks): Sxp[s][d] = sum_{b in slab s} (1 - x[b,d])
// ===========================================================================
__global__ __launch_bounds__(256) void kA(const float* __restrict__ x,
                                          const float* __restrict__ w,
                                          const float* __restrict__ t,
                                          float* __restrict__ xT,
                                          float* __restrict__ tT,
                                          float* __restrict__ wT,
                                          double* __restrict__ Sxp,
                                          double* __restrict__ part) {
  __shared__ float smem[8 * 136];  // 4352 B; transpose roles use 32*33 <= this
  int bid = blockIdx.x, tid = threadIdx.x;
  if (bid < 512) {
    // ---- role P ----
    float (*xl)[136] = (float(*)[136])smem;  // row stride 544B (16B aligned)
    int dg = bid >> 3, sy = bid & 7;
    int d0 = dg * 8, b0 = sy * 128, o = tid;
    {
      int bb = tid >> 1, half = tid & 1;
      float4 g = *(const float4*)&x[(b0 + bb) * DD + d0 + half * 4];
      xl[half * 4 + 0][bb] = g.x;
      xl[half * 4 + 1][bb] = g.y;
      xl[half * 4 + 2][bb] = g.z;
      xl[half * 4 + 3][bb] = g.w;
    }
    __syncthreads();
    double acc[8] = {0, 0, 0, 0, 0, 0, 0, 0};
    // software-pipelined t loads (prefetch next group of 4)
    float tv0 = t[(b0 + 0) * OO + o];
    float tv1 = t[(b0 + 1) * OO + o];
    float tv2 = t[(b0 + 2) * OO + o];
    float tv3 = t[(b0 + 3) * OO + o];
    for (int bb = 0; bb < 128; bb += 4) {
      float nv0, nv1, nv2, nv3;
      if (bb + 4 < 128) {
        nv0 = t[(b0 + bb + 4) * OO + o];
        nv1 = t[(b0 + bb + 5) * OO + o];
        nv2 = t[(b0 + bb + 6) * OO + o];
        nv3 = t[(b0 + bb + 7) * OO + o];
      } else {
        nv0 = nv1 = nv2 = nv3 = 0.0f;
      }
#pragma unroll
      for (int dd = 0; dd < 8; ++dd) {
        float4 xv = *(const float4*)&xl[dd][bb];
        double s01 = (double)fmaxf(xv.x, tv0) + (double)fmaxf(xv.y, tv1);
        double s23 = (double)fmaxf(xv.z, tv2) + (double)fmaxf(xv.w, tv3);
        acc[dd] += s01 + s23;
      }
      tv0 = nv0; tv1 = nv1; tv2 = nv2; tv3 = nv3;
    }
#pragma unroll
    for (int dd = 0; dd < 8; ++dd)
      part[(sy * DD + d0 + dd) * OO + o] = acc[dd];
  } else if (bid < 1024) {
    // ---- role T: x (1024x512) -> xT (512x1024) ----
    float (*tile)[33] = (float(*)[33])smem;
    int r = bid - 512;
    int b0 = (r & 31) * 32, d0 = (r >> 5) * 32;
    int tx = tid & 31, ty = tid >> 5;
    for (int i = 0; i < 32; i += 8)
      tile[ty + i][tx] = x[(b0 + ty + i) * DD + d0 + tx];
    __syncthreads();
    for (int i = 0; i < 32; i += 8)
      xT[(d0 + ty + i) * BB + b0 + tx] = tile[tx][ty + i];
  } else if (bid < 1280) {
    // ---- role Tt: t (1024x256) -> tT (256x1024) ----
    float (*tile)[33] = (float(*)[33])smem;
    int r = bid - 1024;
    int b0 = (r & 31) * 32, o0 = (r >> 5) * 32;
    int tx = tid & 31, ty = tid >> 5;
    for (int i = 0; i < 32; i += 8)
      tile[ty + i][tx] = t[(b0 + ty + i) * OO + o0 + tx];
    __syncthreads();
    for (int i = 0; i < 32; i += 8)
      tT[(o0 + ty + i) * BB + b0 + tx] = tile[tx][ty + i];
  } else if (bid < 1408) {
    // ---- role W: w (512x256) -> wT (256x512) ----
    float (*tile)[33] = (float(*)[33])smem;
    int r = bid - 1280;
    int d0 = (r & 15) * 32, o0 = (r >> 4) * 32;
    int tx = tid & 31, ty = tid >> 5;
    for (int i = 0; i < 32; i += 8)
      tile[ty + i][tx] = w[(d0 + ty + i) * OO + o0 + tx];
    __syncthreads();
    for (int i = 0; i < 32; i += 8)
      wT[(o0 + ty + i) * DD + d0 + tx] = tile[tx][ty + i];
  } else {
    // ---- role S ----
    int r = bid - 1408;  // 0..15
    int sy = r & 7, dh = r >> 3;
    int d = dh * 256 + tid, b0 = sy * 128;
    double s = 0.0;
    for (int b = b0; b < b0 + 128; ++b) s += 1.0 - (double)x[b * DD + d];
    Sxp[sy * DD + d] = s;
  }
}

// ===========================================================================
// kB: per-o tables.
//  bid < 256 (WB): bucket w column (512 buckets over [0,1), trunc quantizer),
//    idx-sort buckets (f64 determinism), exclusive prefix sum P / prefix-min
//    Mx, bucket offsets, global lexicographic min.
//  bid >= 256 (RX): combine partials -> relx column, bucket by value over
//    [rmin,rmax]; eb = round-DOWN f32 bucket lower bound (safe break bound).
// ===========================================================================
__global__ __launch_bounds__(256) void kB(const float* __restrict__ wT,
                                          const double* __restrict__ Sxp,
                                          const double* __restrict__ part,
                                          float* __restrict__ sv_g,
                                          int* __restrict__ si_g,
                                          int* __restrict__ off_g,
                                          double* __restrict__ P_g,
                                          int* __restrict__ Mx_g,
                                          double* __restrict__ rv_g,
                                          int* __restrict__ ri_g,
                                          float* __restrict__ eb_g,
                                          double* __restrict__ hdrW,
                                          int* __restrict__ gmin_g) {
  int bid = blockIdx.x, tid = threadIdx.x;
  int lane = tid & 63, wid = tid >> 6;
  if (bid < OO) {
    int o = bid;
    __shared__ float sv[512];
    __shared__ int si[512];
    __shared__ int cnt[512];
    __shared__ int off[513];
    __shared__ double P[513];
    __shared__ int Mx[513];
    __shared__ double wsc[4];
    __shared__ int wmn[4];
    __shared__ unsigned long long wk[4];
    int i0 = 2 * tid, i1 = 2 * tid + 1;
    float w0 = wT[o * DD + i0], w1 = wT[o * DD + i1];
    cnt[i0] = 0; cnt[i1] = 0;
    __syncthreads();
    int q0 = min(511, max(0, (int)(w0 * 512.0f)));
    int q1 = min(511, max(0, (int)(w1 * 512.0f)));
    int sl0 = atomicAdd(&cnt[q0], 1);
    int sl1 = atomicAdd(&cnt[q1], 1);
    __syncthreads();
    {
      int e0 = cnt[i0], e1 = cnt[i1];
      int s = e0 + e1, v = s;
      for (int d = 1; d < 64; d <<= 1) {
        int u = __shfl_up(v, d);
        if (lane >= d) v += u;
      }
      if (lane == 63) wmn[wid] = v;
      __syncthreads();
      int wp = 0;
      for (int u = 0; u < wid; ++u) wp += wmn[u];
      int ex = wp + (v - s);
      off[i0] = ex; off[i1] = ex + e0;
      if (tid == 255) off[512] = ex + s;
      __syncthreads();
    }
    sv[off[q0] + sl0] = w0; si[off[q0] + sl0] = i0;
    sv[off[q1] + sl1] = w1; si[off[q1] + sl1] = i1;
    __syncthreads();
    for (int q = tid; q < 512; q += 256) {
      int s = off[q], e = off[q + 1];
      for (int i = s + 1; i < e; ++i) {
        int ki = si[i]; float kv = sv[i]; int j = i - 1;
        while (j >= s && si[j] > ki) { si[j + 1] = si[j]; sv[j + 1] = sv[j]; --j; }
        si[j + 1] = ki; sv[j + 1] = kv;
      }
    }
    __syncthreads();
    {
      double e0 = (double)sv[i0], e1 = (double)sv[i1];
      int m0 = si[i0], m1 = si[i1];
      double s = e0 + e1; int mm = min(m0, m1);
      double vs = s; int vm = mm;
      for (int d = 1; d < 64; d <<= 1) {
        double us = __shfl_up(vs, d);
        int um = __shfl_up(vm, d);
        if (lane >= d) { vs += us; vm = min(vm, um); }
      }
      double exs = __shfl_up(vs, 1);
      int exm = __shfl_up(vm, 1);
      if (lane == 0) { exs = 0.0; exm = 0x7fffffff; }
      if (lane == 63) { wsc[wid] = vs; wmn[wid] = vm; }
      __syncthreads();
      double wp = 0.0; int wm = 0x7fffffff;
      for (int u = 0; u < wid; ++u) { wp += wsc[u]; wm = min(wm, wmn[u]); }
      double EX = wp + exs; int EXM = min(wm, exm);
      P[i0] = EX; P[i1] = EX + e0;
      Mx[i0] = EXM; Mx[i1] = min(EXM, m0);
      if (tid == 255) { P[512] = EX + s; Mx[512] = min(EXM, mm); }
      __syncthreads();
    }
    {
      unsigned long long k0 = ((unsigned long long)__float_as_uint(sv[i0]) << 32) | (unsigned)si[i0];
      unsigned long long k1 = ((unsigned long long)__float_as_uint(sv[i1]) << 32) | (unsigned)si[i1];
      unsigned long long kk = k0 < k1 ? k0 : k1;
      for (int d = 32; d > 0; d >>= 1) {
        unsigned long long u = __shfl_down(kk, d);
        kk = u < kk ? u : kk;
      }
      if (lane == 0) wk[wid] = kk;
      __syncthreads();
      if (tid == 0) {
        unsigned long long g = wk[0];
        for (int u = 1; u < 4; ++u) g = wk[u] < g ? wk[u] : g;
        gmin_g[o] = (int)(g & 0xffffffffull);
      }
    }
    for (int i = tid; i < 512; i += 256) {
      sv_g[o * 512 + i] = sv[i];
      si_g[o * 512 + i] = si[i];
    }
    for (int i = tid; i < 513; i += 256) {
      off_g[o * 513 + i] = off[i];
      P_g[o * 513 + i] = P[i];
      Mx_g[o * 513 + i] = Mx[i];
    }
    if (tid == 0) { hdrW[o * 2 + 0] = 512.0 - P[512]; hdrW[o * 2 + 1] = P[512]; }
  } else {
    int o = bid - OO;
    __shared__ double rl[512];
    __shared__ int cnt2[512];
    __shared__ int roff[513];
    __shared__ double rv[512];
    __shared__ int ri[512];
    __shared__ float eb[512];
    __shared__ double wred[8];
    __shared__ int wint[4];
    int i0 = 2 * tid, i1 = 2 * tid + 1;
    {
      double sx0 = 0.0, sx1 = 0.0, a0 = 0.0, a1 = 0.0;
#pragma unroll
      for (int s = 0; s < 8; ++s) {
        sx0 += Sxp[s * DD + i0];
        sx1 += Sxp[s * DD + i1];
        a0 += part[(s * DD + i0) * OO + o];
        a1 += part[(s * DD + i1) * OO + o];
      }
      rl[i0] = 1.0 - (1024.0 - a0) / sx0;
      rl[i1] = 1.0 - (1024.0 - a1) / sx1;
    }
    double mn = fmin(rl[i0], rl[i1]), mx = fmax(rl[i0], rl[i1]);
    for (int d = 32; d > 0; d >>= 1) {
      mn = fmin(mn, __shfl_down(mn, d));
      mx = fmax(mx, __shfl_down(mx, d));
    }
    if (lane == 0) { wred[wid] = mn; wred[4 + wid] = mx; }
    cnt2[i0] = 0; cnt2[i1] = 0;
    __syncthreads();
    double rmin = fmin(fmin(wred[0], wred[1]), fmin(wred[2], wred[3]));
    double rmax = fmax(fmax(wred[4], wred[5]), fmax(wred[6], wred[7]));
    double range = rmax - rmin;
    double scale = (range > 0.0) ? (512.0 / range) : 0.0;
    double bw = range * (1.0 / 512.0);
    double base = rmin - range * 1e-9;  // margin absorbs f64 quantizer rounding
    int q0 = min(511, max(0, (int)((rl[i0] - rmin) * scale)));
    int q1 = min(511, max(0, (int)((rl[i1] - rmin) * scale)));
    int sl0 = atomicAdd(&cnt2[q0], 1);
    int sl1 = atomicAdd(&cnt2[q1], 1);
    __syncthreads();
    {
      int e0 = cnt2[i0], e1 = cnt2[i1];
      int s = e0 + e1, v = s;
      for (int d = 1; d < 64; d <<= 1) {
        int u = __shfl_up(v, d);
        if (lane >= d) v += u;
      }
      if (lane == 63) wint[wid] = v;
      __syncthreads();
      int wp = 0;
      for (int u = 0; u < wid; ++u) wp += wint[u];
      int ex = wp + (v - s);
      roff[i0] = ex; roff[i1] = ex + e0;
      if (tid == 255) roff[512] = ex + s;
      __syncthreads();
    }
    {
      int p0 = roff[q0] + sl0, p1 = roff[q1] + sl1;
      rv[p0] = rl[i0]; ri[p0] = i0;
      eb[p0] = __double2float_rd(base + (double)q0 * bw);  // <= true bound
      rv[p1] = rl[i1]; ri[p1] = i1;
      eb[p1] = __double2float_rd(base + (double)q1 * bw);
    }
    __syncthreads();
    for (int i = tid; i < 512; i += 256) {
      rv_g[o * 512 + i] = rv[i];
      ri_g[o * 512 + i] = ri[i];
      eb_g[o * 512 + i] = eb[i];
    }
  }
}

// ===========================================================================
// kC: per (b,o) queries. Writes TRANSPOSED outputs (coalesced in b);
// kD re-transposes to the final (B,O) layout.
// ===========================================================================
__global__ __launch_bounds__(256) void kC(
    const float* __restrict__ xT, const float* __restrict__ wT,
    const float* __restrict__ tT, const float* __restrict__ sv_g,
    const int* __restrict__ si_g, const int* __restrict__ off_g,
    const double* __restrict__ P_g, const int* __restrict__ Mx_g,
    const double* __restrict__ rv_g, const int* __restrict__ ri_g,
    const float* __restrict__ eb_g, const double* __restrict__ hdrW,
    const int* __restrict__ gmin_g, float* __restrict__ outT0,
    float* __restrict__ outT1) {
  int o = blockIdx.x, tid = threadIdx.x;
  int b = blockIdx.y * 256 + tid;
  __shared__ float sv[512];
  __shared__ int si[512];
  __shared__ int off[513];
  __shared__ double P[513];
  __shared__ int Mx[513];
  __shared__ double rv[512];
  __shared__ int ri[512];
  __shared__ float eb[512];
  __shared__ float wl[512];
  for (int i = tid; i < 512; i += 256) {
    sv[i] = sv_g[o * 512 + i];
    si[i] = si_g[o * 512 + i];
    rv[i] = rv_g[o * 512 + i];
    ri[i] = ri_g[o * 512 + i];
    eb[i] = eb_g[o * 512 + i];
    wl[i] = wT[o * DD + i];
  }
  for (int i = tid; i < 513; i += 256) {
    off[i] = off_g[o * 513 + i];
    P[i] = P_g[o * 513 + i];
    Mx[i] = Mx_g[o * 513 + i];
  }
  __syncthreads();
  double Sw = hdrW[o * 2 + 0], Wtot = hdrW[o * 2 + 1];
  float c = tT[o * BB + b];
  // Q1: prefix count/sum of {w <= c}
  int j = min(511, max(0, (int)(c * 512.0f)));
  int s0 = off[j], e0 = off[j + 1];
  double pre = P[s0];
  int k = s0;
  for (int i = s0; i < e0; ++i) {
    float wv = sv[i];
    if (wv <= c) { pre += (double)wv; ++k; }
  }
  double smax = (Wtot - pre) + (double)c * (double)k;
  double relw = 1.0 - (512.0 - smax) / Sw;
  // Q2: min original index with w <= relw (scan buckets j2 and j2+1)
  int j2 = min(511, max(0, (int)(relw * 512.0)));
  int s2 = off[j2], e2 = off[min(512, j2 + 2)];
  int iw = Mx[s2];
  for (int i = s2; i < e2; ++i)
    if ((double)sv[i] <= relw) iw = min(iw, si[i]);
  if (iw == 0x7fffffff) iw = gmin_g[o];
  // RX: argmin_d max(x, relx), ascending-bucket scan with safe break bound
  float x0 = xT[ri[0] * BB + b], x1 = xT[ri[1] * BB + b];
  float x2 = xT[ri[2] * BB + b], x3 = xT[ri[3] * BB + b];
  float x4 = xT[ri[4] * BB + b], x5 = xT[ri[5] * BB + b];
  float x6 = xT[ri[6] * BB + b], x7 = xT[ri[7] * BB + b];
  double best = 1e300;
  int bix = 0x7fffffff;
  float bestx = 0.0f;
  for (int i = 0; i < 512; ++i) {
    if ((double)eb[i] > best) break;
    int dj = ri[i];
    float xv;
    if (i < 8) {
      xv = (i == 0) ? x0 : (i == 1) ? x1 : (i == 2) ? x2 : (i == 3) ? x3
         : (i == 4) ? x4 : (i == 5) ? x5 : (i == 6) ? x6 : x7;
    } else {
      xv = xT[dj * BB + b];
    }
    double v = fmax((double)xv, rv[i]);
    if (v < best || (v == best && dj < bix)) { best = v; bix = dj; bestx = xv; }
  }
  float ox = fmaxf(bestx, wl[bix]);
  float ow = fmaxf(xT[iw * BB + b], wl[iw]);
  outT0[o * BB + b] = ox;   // coalesced: lanes consecutive in b
  outT1[o * BB + b] = ow;
}

// ===========================================================================
// kD: transpose outT (O x B) -> out (B x O) for both outputs. Both sides
// coalesced via 32x32 LDS tile.
// ===========================================================================
__global__ __launch_bounds__(256) void kD(const float* __restrict__ outT0,
                                          const float* __restrict__ outT1,
                                          float* __restrict__ out) {
  __shared__ float tile[32][33];
  const float* src = blockIdx.z ? outT1 : outT0;
  float* dst = out + (size_t)blockIdx.z * BB * OO;
  int b0 = blockIdx.x * 32, o0 = blockIdx.y * 32;
  int tx = threadIdx.x & 31, ty = threadIdx.x >> 5;
  for (int i = 0; i < 32; i += 8)
    tile[ty + i][tx] = src[(o0 + ty + i) * BB + b0 + tx];
  __syncthreads();
  for (int i = 0; i < 32; i += 8)
    dst[(b0 + ty + i) * OO + o0 + tx] = tile[tx][ty + i];
}

// ===========================================================================
extern "C" void kernel_launch(void* const* d_in, const int* in_sizes, int n_in,
                              void* d_out, int out_size, void* d_ws,
                              size_t ws_size, hipStream_t stream) {
  const float* x = (const float*)d_in[0];  // (B,D)
  const float* w = (const float*)d_in[1];  // (D,O)
  const float* t = (const float*)d_in[2];  // (B,O)
  float* out = (float*)d_out;
  char* ws = (char*)d_ws;

  size_t off = 0;
  float* xT    = (float*)(ws + off);  off += (size_t)DD * BB * 4;       // 2 MB
  float* tT    = (float*)(ws + off);  off += (size_t)OO * BB * 4;       // 1 MB
  float* wT    = (float*)(ws + off);  off += (size_t)OO * DD * 4;       // .5 MB
  double* Sxp  = (double*)(ws + off); off += (size_t)8 * DD * 8;        // 32 KB
  double* part = (double*)(ws + off); off += (size_t)8 * DD * OO * 8;   // 8 MB
  float* sv_g  = (float*)(ws + off);  off += (size_t)OO * 512 * 4;
  int* si_g    = (int*)(ws + off);    off += (size_t)OO * 512 * 4;
  int* off_g   = (int*)(ws + off);    off += (size_t)OO * 513 * 4;
  double* P_g  = (double*)(ws + off); off += (size_t)OO * 513 * 8;
  int* Mx_g    = (int*)(ws + off);    off += (size_t)OO * 513 * 4;
  double* rv_g = (double*)(ws + off); off += (size_t)OO * 512 * 8;
  int* ri_g    = (int*)(ws + off);    off += (size_t)OO * 512 * 4;
  float* eb_g  = (float*)(ws + off);  off += (size_t)OO * 512 * 4;
  double* hdrW = (double*)(ws + off); off += (size_t)OO * 2 * 8;
  int* gmin_g  = (int*)(ws + off);    off += (size_t)OO * 4;
  off = (off + 255) & ~(size_t)255;
  float* outT0 = (float*)(ws + off);  off += (size_t)OO * BB * 4;       // 1 MB
  float* outT1 = (float*)(ws + off);  off += (size_t)OO * BB * 4;       // 1 MB

  kA<<<1424, 256, 0, stream>>>(x, w, t, xT, tT, wT, Sxp, part);
  kB<<<2 * OO, 256, 0, stream>>>(wT, Sxp, part, sv_g, si_g, off_g, P_g, Mx_g,
                                 rv_g, ri_g, eb_g, hdrW, gmin_g);
  kC<<<dim3(OO, BB / 256), 256, 0, stream>>>(xT, wT, tT, sv_g, si_g, off_g,
                                             P_g, Mx_g, rv_g, ri_g, eb_g,
                                             hdrW, gmin_g, outT0, outT1);
  kD<<<dim3(BB / 32, OO / 32, 2), 256, 0, stream>>>(outT0, outT1, out);
}

// Round 6
// 64.948 us; speedup vs baseline: 1.0300x; 1.0300x over previous
//
#include <hip/hip_runtime.h>

#define BB 1024
#define DD 512
#define OO 256

// ===========================================================================
// kA: all-independent roles in one launch:
//   P  (512 blocks): part[s][d][o] = sum_{b in slab s} max(x[b,d], t[b,o])
//   T  (512 blocks): transpose x -> xT[d][b]
//   Tt (256 blocks): transpose t -> tT[o][b]
//   W  (128 blocks): transpose w -> wT[o][d]
//   S  ( 16 blocks): Sxp[s][d] = sum_{b in slab s} (1 - x[b,d])
// ===========================================================================
__global__ __launch_bounds__(256) void kA(const float* __restrict__ x,
                                          const float* __restrict__ w,
                                          const float* __restrict__ t,
                                          float* __restrict__ xT,
                                          float* __restrict__ tT,
                                          float* __restrict__ wT,
                                          double* __restrict__ Sxp,
                                          double* __restrict__ part) {
  __shared__ float smem[8 * 136];  // 4352 B; transpose roles use 32*33 <= this
  int bid = blockIdx.x, tid = threadIdx.x;
  if (bid < 512) {
    // ---- role P ----
    float (*xl)[136] = (float(*)[136])smem;  // row stride 544B (16B aligned)
    int dg = bid >> 3, sy = bid & 7;
    int d0 = dg * 8, b0 = sy * 128, o = tid;
    {
      int bb = tid >> 1, half = tid & 1;
      float4 g = *(const float4*)&x[(b0 + bb) * DD + d0 + half * 4];
      xl[half * 4 + 0][bb] = g.x;
      xl[half * 4 + 1][bb] = g.y;
      xl[half * 4 + 2][bb] = g.z;
      xl[half * 4 + 3][bb] = g.w;
    }
    __syncthreads();
    double acc[8] = {0, 0, 0, 0, 0, 0, 0, 0};
    for (int bb = 0; bb < 128; bb += 4) {
      float tv0 = t[(b0 + bb + 0) * OO + o];
      float tv1 = t[(b0 + bb + 1) * OO + o];
      float tv2 = t[(b0 + bb + 2) * OO + o];
      float tv3 = t[(b0 + bb + 3) * OO + o];
#pragma unroll
      for (int dd = 0; dd < 8; ++dd) {
        float4 xv = *(const float4*)&xl[dd][bb];
        double s01 = (double)fmaxf(xv.x, tv0) + (double)fmaxf(xv.y, tv1);
        double s23 = (double)fmaxf(xv.z, tv2) + (double)fmaxf(xv.w, tv3);
        acc[dd] += s01 + s23;
      }
    }
#pragma unroll
    for (int dd = 0; dd < 8; ++dd)
      part[(sy * DD + d0 + dd) * OO + o] = acc[dd];
  } else if (bid < 1024) {
    // ---- role T: x (1024x512) -> xT (512x1024) ----
    float (*tile)[33] = (float(*)[33])smem;
    int r = bid - 512;
    int b0 = (r & 31) * 32, d0 = (r >> 5) * 32;
    int tx = tid & 31, ty = tid >> 5;
    for (int i = 0; i < 32; i += 8)
      tile[ty + i][tx] = x[(b0 + ty + i) * DD + d0 + tx];
    __syncthreads();
    for (int i = 0; i < 32; i += 8)
      xT[(d0 + ty + i) * BB + b0 + tx] = tile[tx][ty + i];
  } else if (bid < 1280) {
    // ---- role Tt: t (1024x256) -> tT (256x1024) ----
    float (*tile)[33] = (float(*)[33])smem;
    int r = bid - 1024;
    int b0 = (r & 31) * 32, o0 = (r >> 5) * 32;
    int tx = tid & 31, ty = tid >> 5;
    for (int i = 0; i < 32; i += 8)
      tile[ty + i][tx] = t[(b0 + ty + i) * OO + o0 + tx];
    __syncthreads();
    for (int i = 0; i < 32; i += 8)
      tT[(o0 + ty + i) * BB + b0 + tx] = tile[tx][ty + i];
  } else if (bid < 1408) {
    // ---- role W: w (512x256) -> wT (256x512) ----
    float (*tile)[33] = (float(*)[33])smem;
    int r = bid - 1280;
    int d0 = (r & 15) * 32, o0 = (r >> 4) * 32;
    int tx = tid & 31, ty = tid >> 5;
    for (int i = 0; i < 32; i += 8)
      tile[ty + i][tx] = w[(d0 + ty + i) * OO + o0 + tx];
    __syncthreads();
    for (int i = 0; i < 32; i += 8)
      wT[(o0 + ty + i) * DD + d0 + tx] = tile[tx][ty + i];
  } else {
    // ---- role S ----
    int r = bid - 1408;  // 0..15
    int sy = r & 7, dh = r >> 3;
    int d = dh * 256 + tid, b0 = sy * 128;
    double s = 0.0;
    for (int b = b0; b < b0 + 128; ++b) s += 1.0 - (double)x[b * DD + d];
    Sxp[sy * DD + d] = s;
  }
}

// ===========================================================================
// kB: per-o tables.
//  bid < 256 (WB): bucket w column (512 buckets over [0,1), trunc quantizer),
//    idx-sort buckets (f64 determinism), exclusive prefix sum P / prefix-min
//    Mx, bucket offsets, global lexicographic min.
//  bid >= 256 (RX): combine partials -> relx column, bucket by value over
//    [rmin,rmax]; eb = round-DOWN f32 bucket lower bound (safe break bound).
// ===========================================================================
__global__ __launch_bounds__(256) void kB(const float* __restrict__ wT,
                                          const double* __restrict__ Sxp,
                                          const double* __restrict__ part,
                                          float* __restrict__ sv_g,
                                          int* __restrict__ si_g,
                                          int* __restrict__ off_g,
                                          double* __restrict__ P_g,
                                          int* __restrict__ Mx_g,
                                          double* __restrict__ rv_g,
                                          int* __restrict__ ri_g,
                                          float* __restrict__ eb_g,
                                          double* __restrict__ hdrW,
                                          int* __restrict__ gmin_g) {
  int bid = blockIdx.x, tid = threadIdx.x;
  int lane = tid & 63, wid = tid >> 6;
  if (bid < OO) {
    int o = bid;
    __shared__ float sv[512];
    __shared__ int si[512];
    __shared__ int cnt[512];
    __shared__ int off[513];
    __shared__ double P[513];
    __shared__ int Mx[513];
    __shared__ double wsc[4];
    __shared__ int wmn[4];
    __shared__ unsigned long long wk[4];
    int i0 = 2 * tid, i1 = 2 * tid + 1;
    float w0 = wT[o * DD + i0], w1 = wT[o * DD + i1];
    cnt[i0] = 0; cnt[i1] = 0;
    __syncthreads();
    int q0 = min(511, max(0, (int)(w0 * 512.0f)));
    int q1 = min(511, max(0, (int)(w1 * 512.0f)));
    int sl0 = atomicAdd(&cnt[q0], 1);
    int sl1 = atomicAdd(&cnt[q1], 1);
    __syncthreads();
    {
      int e0 = cnt[i0], e1 = cnt[i1];
      int s = e0 + e1, v = s;
      for (int d = 1; d < 64; d <<= 1) {
        int u = __shfl_up(v, d);
        if (lane >= d) v += u;
      }
      if (lane == 63) wmn[wid] = v;
      __syncthreads();
      int wp = 0;
      for (int u = 0; u < wid; ++u) wp += wmn[u];
      int ex = wp + (v - s);
      off[i0] = ex; off[i1] = ex + e0;
      if (tid == 255) off[512] = ex + s;
      __syncthreads();
    }
    sv[off[q0] + sl0] = w0; si[off[q0] + sl0] = i0;
    sv[off[q1] + sl1] = w1; si[off[q1] + sl1] = i1;
    __syncthreads();
    for (int q = tid; q < 512; q += 256) {
      int s = off[q], e = off[q + 1];
      for (int i = s + 1; i < e; ++i) {
        int ki = si[i]; float kv = sv[i]; int j = i - 1;
        while (j >= s && si[j] > ki) { si[j + 1] = si[j]; sv[j + 1] = sv[j]; --j; }
        si[j + 1] = ki; sv[j + 1] = kv;
      }
    }
    __syncthreads();
    {
      double e0 = (double)sv[i0], e1 = (double)sv[i1];
      int m0 = si[i0], m1 = si[i1];
      double s = e0 + e1; int mm = min(m0, m1);
      double vs = s; int vm = mm;
      for (int d = 1; d < 64; d <<= 1) {
        double us = __shfl_up(vs, d);
        int um = __shfl_up(vm, d);
        if (lane >= d) { vs += us; vm = min(vm, um); }
      }
      double exs = __shfl_up(vs, 1);
      int exm = __shfl_up(vm, 1);
      if (lane == 0) { exs = 0.0; exm = 0x7fffffff; }
      if (lane == 63) { wsc[wid] = vs; wmn[wid] = vm; }
      __syncthreads();
      double wp = 0.0; int wm = 0x7fffffff;
      for (int u = 0; u < wid; ++u) { wp += wsc[u]; wm = min(wm, wmn[u]); }
      double EX = wp + exs; int EXM = min(wm, exm);
      P[i0] = EX; P[i1] = EX + e0;
      Mx[i0] = EXM; Mx[i1] = min(EXM, m0);
      if (tid == 255) { P[512] = EX + s; Mx[512] = min(EXM, mm); }
      __syncthreads();
    }
    {
      unsigned long long k0 = ((unsigned long long)__float_as_uint(sv[i0]) << 32) | (unsigned)si[i0];
      unsigned long long k1 = ((unsigned long long)__float_as_uint(sv[i1]) << 32) | (unsigned)si[i1];
      unsigned long long kk = k0 < k1 ? k0 : k1;
      for (int d = 32; d > 0; d >>= 1) {
        unsigned long long u = __shfl_down(kk, d);
        kk = u < kk ? u : kk;
      }
      if (lane == 0) wk[wid] = kk;
      __syncthreads();
      if (tid == 0) {
        unsigned long long g = wk[0];
        for (int u = 1; u < 4; ++u) g = wk[u] < g ? wk[u] : g;
        gmin_g[o] = (int)(g & 0xffffffffull);
      }
    }
    for (int i = tid; i < 512; i += 256) {
      sv_g[o * 512 + i] = sv[i];
      si_g[o * 512 + i] = si[i];
    }
    for (int i = tid; i < 513; i += 256) {
      off_g[o * 513 + i] = off[i];
      P_g[o * 513 + i] = P[i];
      Mx_g[o * 513 + i] = Mx[i];
    }
    if (tid == 0) { hdrW[o * 2 + 0] = 512.0 - P[512]; hdrW[o * 2 + 1] = P[512]; }
  } else {
    int o = bid - OO;
    __shared__ double rl[512];
    __shared__ int cnt2[512];
    __shared__ int roff[513];
    __shared__ double rv[512];
    __shared__ int ri[512];
    __shared__ float eb[512];
    __shared__ double wred[8];
    __shared__ int wint[4];
    int i0 = 2 * tid, i1 = 2 * tid + 1;
    {
      double sx0 = 0.0, sx1 = 0.0, a0 = 0.0, a1 = 0.0;
#pragma unroll
      for (int s = 0; s < 8; ++s) {
        sx0 += Sxp[s * DD + i0];
        sx1 += Sxp[s * DD + i1];
        a0 += part[(s * DD + i0) * OO + o];
        a1 += part[(s * DD + i1) * OO + o];
      }
      rl[i0] = 1.0 - (1024.0 - a0) / sx0;
      rl[i1] = 1.0 - (1024.0 - a1) / sx1;
    }
    double mn = fmin(rl[i0], rl[i1]), mx = fmax(rl[i0], rl[i1]);
    for (int d = 32; d > 0; d >>= 1) {
      mn = fmin(mn, __shfl_down(mn, d));
      mx = fmax(mx, __shfl_down(mx, d));
    }
    if (lane == 0) { wred[wid] = mn; wred[4 + wid] = mx; }
    cnt2[i0] = 0; cnt2[i1] = 0;
    __syncthreads();
    double rmin = fmin(fmin(wred[0], wred[1]), fmin(wred[2], wred[3]));
    double rmax = fmax(fmax(wred[4], wred[5]), fmax(wred[6], wred[7]));
    double range = rmax - rmin;
    double scale = (range > 0.0) ? (512.0 / range) : 0.0;
    double bw = range * (1.0 / 512.0);
    double base = rmin - range * 1e-9;  // margin absorbs f64 quantizer rounding
    int q0 = min(511, max(0, (int)((rl[i0] - rmin) * scale)));
    int q1 = min(511, max(0, (int)((rl[i1] - rmin) * scale)));
    int sl0 = atomicAdd(&cnt2[q0], 1);
    int sl1 = atomicAdd(&cnt2[q1], 1);
    __syncthreads();
    {
      int e0 = cnt2[i0], e1 = cnt2[i1];
      int s = e0 + e1, v = s;
      for (int d = 1; d < 64; d <<= 1) {
        int u = __shfl_up(v, d);
        if (lane >= d) v += u;
      }
      if (lane == 63) wint[wid] = v;
      __syncthreads();
      int wp = 0;
      for (int u = 0; u < wid; ++u) wp += wint[u];
      int ex = wp + (v - s);
      roff[i0] = ex; roff[i1] = ex + e0;
      if (tid == 255) roff[512] = ex + s;
      __syncthreads();
    }
    {
      int p0 = roff[q0] + sl0, p1 = roff[q1] + sl1;
      rv[p0] = rl[i0]; ri[p0] = i0;
      eb[p0] = __double2float_rd(base + (double)q0 * bw);  // <= true bound
      rv[p1] = rl[i1]; ri[p1] = i1;
      eb[p1] = __double2float_rd(base + (double)q1 * bw);
    }
    __syncthreads();
    for (int i = tid; i < 512; i += 256) {
      rv_g[o * 512 + i] = rv[i];
      ri_g[o * 512 + i] = ri[i];
      eb_g[o * 512 + i] = eb[i];
    }
  }
}

// ===========================================================================
// kC: per (b,o) queries. Stage ONLY the RX-scan arrays (rv/ri/eb — reused
// per-thread with lane-broadcast); w-side tables are touched at 2-6 indices
// per thread and read straight from L2.
// ===========================================================================
__global__ __launch_bounds__(256) void kC(
    const float* __restrict__ xT, const float* __restrict__ wT,
    const float* __restrict__ tT, const float* __restrict__ sv_g,
    const int* __restrict__ si_g, const int* __restrict__ off_g,
    const double* __restrict__ P_g, const int* __restrict__ Mx_g,
    const double* __restrict__ rv_g, const int* __restrict__ ri_g,
    const float* __restrict__ eb_g, const double* __restrict__ hdrW,
    const int* __restrict__ gmin_g, float* __restrict__ out) {
  int o = blockIdx.x, tid = threadIdx.x;
  int b = blockIdx.y * 256 + tid;
  __shared__ double rv[512];
  __shared__ int ri[512];
  __shared__ float eb[512];
  for (int i = tid; i < 512; i += 256) {
    rv[i] = rv_g[o * 512 + i];
    ri[i] = ri_g[o * 512 + i];
    eb[i] = eb_g[o * 512 + i];
  }
  __syncthreads();
  const float* sv = sv_g + o * 512;
  const int* si = si_g + o * 512;
  const int* off = off_g + o * 513;
  const double* P = P_g + o * 513;
  const int* Mx = Mx_g + o * 513;
  const float* wl = wT + o * DD;
  double Sw = hdrW[o * 2 + 0], Wtot = hdrW[o * 2 + 1];
  float c = tT[o * BB + b];
  // Q1: prefix count/sum of {w <= c}
  int j = min(511, max(0, (int)(c * 512.0f)));
  int s0 = off[j], e0 = off[j + 1];
  double pre = P[s0];
  int k = s0;
  for (int i = s0; i < e0; ++i) {
    float wv = sv[i];
    if (wv <= c) { pre += (double)wv; ++k; }
  }
  double smax = (Wtot - pre) + (double)c * (double)k;
  double relw = 1.0 - (512.0 - smax) / Sw;
  // Q2: min original index with w <= relw (scan buckets j2 and j2+1)
  int j2 = min(511, max(0, (int)(relw * 512.0)));
  int s2 = off[j2], e2 = off[min(512, j2 + 2)];
  int iw = Mx[s2];
  for (int i = s2; i < e2; ++i)
    if ((double)sv[i] <= relw) iw = min(iw, si[i]);
  if (iw == 0x7fffffff) iw = gmin_g[o];
  // RX: argmin_d max(x, relx), ascending-bucket scan with safe break bound
  float x0 = xT[ri[0] * BB + b], x1 = xT[ri[1] * BB + b];
  float x2 = xT[ri[2] * BB + b], x3 = xT[ri[3] * BB + b];
  float x4 = xT[ri[4] * BB + b], x5 = xT[ri[5] * BB + b];
  float x6 = xT[ri[6] * BB + b], x7 = xT[ri[7] * BB + b];
  double best = 1e300;
  int bix = 0x7fffffff;
  float bestx = 0.0f;
  for (int i = 0; i < 512; ++i) {
    if ((double)eb[i] > best) break;
    int dj = ri[i];
    float xv;
    if (i < 8) {
      xv = (i == 0) ? x0 : (i == 1) ? x1 : (i == 2) ? x2 : (i == 3) ? x3
         : (i == 4) ? x4 : (i == 5) ? x5 : (i == 6) ? x6 : x7;
    } else {
      xv = xT[dj * BB + b];
    }
    double v = fmax((double)xv, rv[i]);
    if (v < best || (v == best && dj < bix)) { best = v; bix = dj; bestx = xv; }
  }
  float ox = fmaxf(bestx, wl[bix]);
  float ow = fmaxf(xT[iw * BB + b], wl[iw]);
  out[b * OO + o] = ox;
  out[BB * OO + b * OO + o] = ow;
}

// ===========================================================================
extern "C" void kernel_launch(void* const* d_in, const int* in_sizes, int n_in,
                              void* d_out, int out_size, void* d_ws,
                              size_t ws_size, hipStream_t stream) {
  const float* x = (const float*)d_in[0];  // (B,D)
  const float* w = (const float*)d_in[1];  // (D,O)
  const float* t = (const float*)d_in[2];  // (B,O)
  float* out = (float*)d_out;
  char* ws = (char*)d_ws;

  size_t off = 0;
  float* xT    = (float*)(ws + off);  off += (size_t)DD * BB * 4;       // 2 MB
  float* tT    = (float*)(ws + off);  off += (size_t)OO * BB * 4;       // 1 MB
  float* wT    = (float*)(ws + off);  off += (size_t)OO * DD * 4;       // .5 MB
  double* Sxp  = (double*)(ws + off); off += (size_t)8 * DD * 8;        // 32 KB
  double* part = (double*)(ws + off); off += (size_t)8 * DD * OO * 8;   // 8 MB
  float* sv_g  = (float*)(ws + off);  off += (size_t)OO * 512 * 4;
  int* si_g    = (int*)(ws + off);    off += (size_t)OO * 512 * 4;
  int* off_g   = (int*)(ws + off);    off += (size_t)OO * 513 * 4;
  double* P_g  = (double*)(ws + off); off += (size_t)OO * 513 * 8;
  int* Mx_g    = (int*)(ws + off);    off += (size_t)OO * 513 * 4;
  double* rv_g = (double*)(ws + off); off += (size_t)OO * 512 * 8;
  int* ri_g    = (int*)(ws + off);    off += (size_t)OO * 512 * 4;
  float* eb_g  = (float*)(ws + off);  off += (size_t)OO * 512 * 4;
  double* hdrW = (double*)(ws + off); off += (size_t)OO * 2 * 8;
  int* gmin_g  = (int*)(ws + off);    off += (size_t)OO * 4;

  kA<<<1424, 256, 0, stream>>>(x, w, t, xT, tT, wT, Sxp, part);
  kB<<<2 * OO, 256, 0, stream>>>(wT, Sxp, part, sv_g, si_g, off_g, P_g, Mx_g,
                                 rv_g, ri_g, eb_g, hdrW, gmin_g);
  kC<<<dim3(OO, BB / 256), 256, 0, stream>>>(xT, wT, tT, sv_g, si_g, off_g,
                                             P_g, Mx_g, rv_g, ri_g, eb_g,
                                             hdrW, gmin_g, out);
}

// Round 7
// 58.721 us; speedup vs baseline: 1.1392x; 1.1060x over previous
//
#include <hip/hip_runtime.h>

#define BB 1024
#define DD 512
#define OO 256

// ===========================================================================
// kA: all-independent roles in one launch:
//   P  (512 blocks): part[(o*8+s)*DD+d] = sum_{b in slab s} max(x[b,d], t[b,o])
//   T  (512 blocks): transpose x -> xT[d][b]
//   Tt (256 blocks): transpose t -> tT[o][b]
//   W  (128 blocks): transpose w -> wT[o][d]
//   S  ( 16 blocks): Sxp[d*8+s] = sum_{b in slab s} (1 - x[b,d])
// part/Sxp are d-innermost so kB's fixed-o reads are lane-coalesced; the
// kA-side writes are one contiguous 64B sector per lane (no amplification).
// ===========================================================================
__global__ __launch_bounds__(256) void kA(const float* __restrict__ x,
                                          const float* __restrict__ w,
                                          const float* __restrict__ t,
                                          float* __restrict__ xT,
                                          float* __restrict__ tT,
                                          float* __restrict__ wT,
                                          double* __restrict__ Sxp,
                                          double* __restrict__ part) {
  __shared__ float smem[8 * 136];  // 4352 B; transpose roles use 32*33 <= this
  int bid = blockIdx.x, tid = threadIdx.x;
  if (bid < 512) {
    // ---- role P ----
    float (*xl)[136] = (float(*)[136])smem;  // row stride 544B (16B aligned)
    int dg = bid >> 3, sy = bid & 7;
    int d0 = dg * 8, b0 = sy * 128, o = tid;
    {
      int bb = tid >> 1, half = tid & 1;
      float4 g = *(const float4*)&x[(b0 + bb) * DD + d0 + half * 4];
      xl[half * 4 + 0][bb] = g.x;
      xl[half * 4 + 1][bb] = g.y;
      xl[half * 4 + 2][bb] = g.z;
      xl[half * 4 + 3][bb] = g.w;
    }
    __syncthreads();
    double acc[8] = {0, 0, 0, 0, 0, 0, 0, 0};
    for (int bb = 0; bb < 128; bb += 4) {
      float tv0 = t[(b0 + bb + 0) * OO + o];
      float tv1 = t[(b0 + bb + 1) * OO + o];
      float tv2 = t[(b0 + bb + 2) * OO + o];
      float tv3 = t[(b0 + bb + 3) * OO + o];
#pragma unroll
      for (int dd = 0; dd < 8; ++dd) {
        float4 xv = *(const float4*)&xl[dd][bb];
        double s01 = (double)fmaxf(xv.x, tv0) + (double)fmaxf(xv.y, tv1);
        double s23 = (double)fmaxf(xv.z, tv2) + (double)fmaxf(xv.w, tv3);
        acc[dd] += s01 + s23;
      }
    }
#pragma unroll
    for (int dd = 0; dd < 8; ++dd)
      part[((size_t)o * 8 + sy) * DD + d0 + dd] = acc[dd];
  } else if (bid < 1024) {
    // ---- role T: x (1024x512) -> xT (512x1024) ----
    float (*tile)[33] = (float(*)[33])smem;
    int r = bid - 512;
    int b0 = (r & 31) * 32, d0 = (r >> 5) * 32;
    int tx = tid & 31, ty = tid >> 5;
    for (int i = 0; i < 32; i += 8)
      tile[ty + i][tx] = x[(b0 + ty + i) * DD + d0 + tx];
    __syncthreads();
    for (int i = 0; i < 32; i += 8)
      xT[(d0 + ty + i) * BB + b0 + tx] = tile[tx][ty + i];
  } else if (bid < 1280) {
    // ---- role Tt: t (1024x256) -> tT (256x1024) ----
    float (*tile)[33] = (float(*)[33])smem;
    int r = bid - 1024;
    int b0 = (r & 31) * 32, o0 = (r >> 5) * 32;
    int tx = tid & 31, ty = tid >> 5;
    for (int i = 0; i < 32; i += 8)
      tile[ty + i][tx] = t[(b0 + ty + i) * OO + o0 + tx];
    __syncthreads();
    for (int i = 0; i < 32; i += 8)
      tT[(o0 + ty + i) * BB + b0 + tx] = tile[tx][ty + i];
  } else if (bid < 1408) {
    // ---- role W: w (512x256) -> wT (256x512) ----
    float (*tile)[33] = (float(*)[33])smem;
    int r = bid - 1280;
    int d0 = (r & 15) * 32, o0 = (r >> 4) * 32;
    int tx = tid & 31, ty = tid >> 5;
    for (int i = 0; i < 32; i += 8)
      tile[ty + i][tx] = w[(d0 + ty + i) * OO + o0 + tx];
    __syncthreads();
    for (int i = 0; i < 32; i += 8)
      wT[(o0 + ty + i) * DD + d0 + tx] = tile[tx][ty + i];
  } else {
    // ---- role S ----
    int r = bid - 1408;  // 0..15
    int sy = r & 7, dh = r >> 3;
    int d = dh * 256 + tid, b0 = sy * 128;
    double s = 0.0;
    for (int b = b0; b < b0 + 128; ++b) s += 1.0 - (double)x[b * DD + d];
    Sxp[(size_t)d * 8 + sy] = s;
  }
}

// ===========================================================================
// kB: per-o tables.
//  bid < 256 (WB): bucket w column (512 buckets over [0,1), trunc quantizer),
//    idx-sort buckets (f64 determinism), exclusive prefix sum P / prefix-min
//    Mx, bucket offsets, global lexicographic min.
//  bid >= 256 (RX): combine partials -> relx column (now lane-coalesced
//    reads), bucket by value over [rmin,rmax]; eb = round-DOWN f32 bucket
//    lower bound (safe break bound).
// ===========================================================================
__global__ __launch_bounds__(256) void kB(const float* __restrict__ wT,
                                          const double* __restrict__ Sxp,
                                          const double* __restrict__ part,
                                          float* __restrict__ sv_g,
                                          int* __restrict__ si_g,
                                          int* __restrict__ off_g,
                                          double* __restrict__ P_g,
                                          int* __restrict__ Mx_g,
                                          double* __restrict__ rv_g,
                                          int* __restrict__ ri_g,
                                          float* __restrict__ eb_g,
                                          double* __restrict__ hdrW,
                                          int* __restrict__ gmin_g) {
  int bid = blockIdx.x, tid = threadIdx.x;
  int lane = tid & 63, wid = tid >> 6;
  if (bid < OO) {
    int o = bid;
    __shared__ float sv[512];
    __shared__ int si[512];
    __shared__ int cnt[512];
    __shared__ int off[513];
    __shared__ double P[513];
    __shared__ int Mx[513];
    __shared__ double wsc[4];
    __shared__ int wmn[4];
    __shared__ unsigned long long wk[4];
    int i0 = 2 * tid, i1 = 2 * tid + 1;
    float w0 = wT[o * DD + i0], w1 = wT[o * DD + i1];
    cnt[i0] = 0; cnt[i1] = 0;
    __syncthreads();
    int q0 = min(511, max(0, (int)(w0 * 512.0f)));
    int q1 = min(511, max(0, (int)(w1 * 512.0f)));
    int sl0 = atomicAdd(&cnt[q0], 1);
    int sl1 = atomicAdd(&cnt[q1], 1);
    __syncthreads();
    {
      int e0 = cnt[i0], e1 = cnt[i1];
      int s = e0 + e1, v = s;
      for (int d = 1; d < 64; d <<= 1) {
        int u = __shfl_up(v, d);
        if (lane >= d) v += u;
      }
      if (lane == 63) wmn[wid] = v;
      __syncthreads();
      int wp = 0;
      for (int u = 0; u < wid; ++u) wp += wmn[u];
      int ex = wp + (v - s);
      off[i0] = ex; off[i1] = ex + e0;
      if (tid == 255) off[512] = ex + s;
      __syncthreads();
    }
    sv[off[q0] + sl0] = w0; si[off[q0] + sl0] = i0;
    sv[off[q1] + sl1] = w1; si[off[q1] + sl1] = i1;
    __syncthreads();
    for (int q = tid; q < 512; q += 256) {
      int s = off[q], e = off[q + 1];
      for (int i = s + 1; i < e; ++i) {
        int ki = si[i]; float kv = sv[i]; int j = i - 1;
        while (j >= s && si[j] > ki) { si[j + 1] = si[j]; sv[j + 1] = sv[j]; --j; }
        si[j + 1] = ki; sv[j + 1] = kv;
      }
    }
    __syncthreads();
    {
      double e0 = (double)sv[i0], e1 = (double)sv[i1];
      int m0 = si[i0], m1 = si[i1];
      double s = e0 + e1; int mm = min(m0, m1);
      double vs = s; int vm = mm;
      for (int d = 1; d < 64; d <<= 1) {
        double us = __shfl_up(vs, d);
        int um = __shfl_up(vm, d);
        if (lane >= d) { vs += us; vm = min(vm, um); }
      }
      double exs = __shfl_up(vs, 1);
      int exm = __shfl_up(vm, 1);
      if (lane == 0) { exs = 0.0; exm = 0x7fffffff; }
      if (lane == 63) { wsc[wid] = vs; wmn[wid] = vm; }
      __syncthreads();
      double wp = 0.0; int wm = 0x7fffffff;
      for (int u = 0; u < wid; ++u) { wp += wsc[u]; wm = min(wm, wmn[u]); }
      double EX = wp + exs; int EXM = min(wm, exm);
      P[i0] = EX; P[i1] = EX + e0;
      Mx[i0] = EXM; Mx[i1] = min(EXM, m0);
      if (tid == 255) { P[512] = EX + s; Mx[512] = min(EXM, mm); }
      __syncthreads();
    }
    {
      unsigned long long k0 = ((unsigned long long)__float_as_uint(sv[i0]) << 32) | (unsigned)si[i0];
      unsigned long long k1 = ((unsigned long long)__float_as_uint(sv[i1]) << 32) | (unsigned)si[i1];
      unsigned long long kk = k0 < k1 ? k0 : k1;
      for (int d = 32; d > 0; d >>= 1) {
        unsigned long long u = __shfl_down(kk, d);
        kk = u < kk ? u : kk;
      }
      if (lane == 0) wk[wid] = kk;
      __syncthreads();
      if (tid == 0) {
        unsigned long long g = wk[0];
        for (int u = 1; u < 4; ++u) g = wk[u] < g ? wk[u] : g;
        gmin_g[o] = (int)(g & 0xffffffffull);
      }
    }
    for (int i = tid; i < 512; i += 256) {
      sv_g[o * 512 + i] = sv[i];
      si_g[o * 512 + i] = si[i];
    }
    for (int i = tid; i < 513; i += 256) {
      off_g[o * 513 + i] = off[i];
      P_g[o * 513 + i] = P[i];
      Mx_g[o * 513 + i] = Mx[i];
    }
    if (tid == 0) { hdrW[o * 2 + 0] = 512.0 - P[512]; hdrW[o * 2 + 1] = P[512]; }
  } else {
    int o = bid - OO;
    __shared__ double rl[512];
    __shared__ int cnt2[512];
    __shared__ int roff[513];
    __shared__ double rv[512];
    __shared__ int ri[512];
    __shared__ float eb[512];
    __shared__ double wred[8];
    __shared__ int wint[4];
    int i0 = 2 * tid, i1 = 2 * tid + 1;
    {
      double sx0 = 0.0, sx1 = 0.0, a0 = 0.0, a1 = 0.0;
#pragma unroll
      for (int s = 0; s < 8; ++s) {
        sx0 += Sxp[(size_t)i0 * 8 + s];
        sx1 += Sxp[(size_t)i1 * 8 + s];
        a0 += part[((size_t)o * 8 + s) * DD + i0];
        a1 += part[((size_t)o * 8 + s) * DD + i1];
      }
      rl[i0] = 1.0 - (1024.0 - a0) / sx0;
      rl[i1] = 1.0 - (1024.0 - a1) / sx1;
    }
    double mn = fmin(rl[i0], rl[i1]), mx = fmax(rl[i0], rl[i1]);
    for (int d = 32; d > 0; d >>= 1) {
      mn = fmin(mn, __shfl_down(mn, d));
      mx = fmax(mx, __shfl_down(mx, d));
    }
    if (lane == 0) { wred[wid] = mn; wred[4 + wid] = mx; }
    cnt2[i0] = 0; cnt2[i1] = 0;
    __syncthreads();
    double rmin = fmin(fmin(wred[0], wred[1]), fmin(wred[2], wred[3]));
    double rmax = fmax(fmax(wred[4], wred[5]), fmax(wred[6], wred[7]));
    double range = rmax - rmin;
    double scale = (range > 0.0) ? (512.0 / range) : 0.0;
    double bw = range * (1.0 / 512.0);
    double base = rmin - range * 1e-9;  // margin absorbs f64 quantizer rounding
    int q0 = min(511, max(0, (int)((rl[i0] - rmin) * scale)));
    int q1 = min(511, max(0, (int)((rl[i1] - rmin) * scale)));
    int sl0 = atomicAdd(&cnt2[q0], 1);
    int sl1 = atomicAdd(&cnt2[q1], 1);
    __syncthreads();
    {
      int e0 = cnt2[i0], e1 = cnt2[i1];
      int s = e0 + e1, v = s;
      for (int d = 1; d < 64; d <<= 1) {
        int u = __shfl_up(v, d);
        if (lane >= d) v += u;
      }
      if (lane == 63) wint[wid] = v;
      __syncthreads();
      int wp = 0;
      for (int u = 0; u < wid; ++u) wp += wint[u];
      int ex = wp + (v - s);
      roff[i0] = ex; roff[i1] = ex + e0;
      if (tid == 255) roff[512] = ex + s;
      __syncthreads();
    }
    {
      int p0 = roff[q0] + sl0, p1 = roff[q1] + sl1;
      rv[p0] = rl[i0]; ri[p0] = i0;
      eb[p0] = __double2float_rd(base + (double)q0 * bw);  // <= true bound
      rv[p1] = rl[i1]; ri[p1] = i1;
      eb[p1] = __double2float_rd(base + (double)q1 * bw);
    }
    __syncthreads();
    for (int i = tid; i < 512; i += 256) {
      rv_g[o * 512 + i] = rv[i];
      ri_g[o * 512 + i] = ri[i];
      eb_g[o * 512 + i] = eb[i];
    }
  }
}

// ===========================================================================
// kC: per (b,o) queries (R4 version: full LDS staging, direct out writes).
// ===========================================================================
__global__ __launch_bounds__(256) void kC(
    const float* __restrict__ xT, const float* __restrict__ wT,
    const float* __restrict__ tT, const float* __restrict__ sv_g,
    const int* __restrict__ si_g, const int* __restrict__ off_g,
    const double* __restrict__ P_g, const int* __restrict__ Mx_g,
    const double* __restrict__ rv_g, const int* __restrict__ ri_g,
    const float* __restrict__ eb_g, const double* __restrict__ hdrW,
    const int* __restrict__ gmin_g, float* __restrict__ out) {
  int o = blockIdx.x, tid = threadIdx.x;
  int b = blockIdx.y * 256 + tid;
  __shared__ float sv[512];
  __shared__ int si[512];
  __shared__ int off[513];
  __shared__ double P[513];
  __shared__ int Mx[513];
  __shared__ double rv[512];
  __shared__ int ri[512];
  __shared__ float eb[512];
  __shared__ float wl[512];
  for (int i = tid; i < 512; i += 256) {
    sv[i] = sv_g[o * 512 + i];
    si[i] = si_g[o * 512 + i];
    rv[i] = rv_g[o * 512 + i];
    ri[i] = ri_g[o * 512 + i];
    eb[i] = eb_g[o * 512 + i];
    wl[i] = wT[o * DD + i];
  }
  for (int i = tid; i < 513; i += 256) {
    off[i] = off_g[o * 513 + i];
    P[i] = P_g[o * 513 + i];
    Mx[i] = Mx_g[o * 513 + i];
  }
  __syncthreads();
  double Sw = hdrW[o * 2 + 0], Wtot = hdrW[o * 2 + 1];
  float c = tT[o * BB + b];
  // Q1: prefix count/sum of {w <= c}
  int j = min(511, max(0, (int)(c * 512.0f)));
  int s0 = off[j], e0 = off[j + 1];
  double pre = P[s0];
  int k = s0;
  for (int i = s0; i < e0; ++i) {
    float wv = sv[i];
    if (wv <= c) { pre += (double)wv; ++k; }
  }
  double smax = (Wtot - pre) + (double)c * (double)k;
  double relw = 1.0 - (512.0 - smax) / Sw;
  // Q2: min original index with w <= relw (scan buckets j2 and j2+1)
  int j2 = min(511, max(0, (int)(relw * 512.0)));
  int s2 = off[j2], e2 = off[min(512, j2 + 2)];
  int iw = Mx[s2];
  for (int i = s2; i < e2; ++i)
    if ((double)sv[i] <= relw) iw = min(iw, si[i]);
  if (iw == 0x7fffffff) iw = gmin_g[o];
  // RX: argmin_d max(x, relx), ascending-bucket scan with safe break bound
  float x0 = xT[ri[0] * BB + b], x1 = xT[ri[1] * BB + b];
  float x2 = xT[ri[2] * BB + b], x3 = xT[ri[3] * BB + b];
  float x4 = xT[ri[4] * BB + b], x5 = xT[ri[5] * BB + b];
  float x6 = xT[ri[6] * BB + b], x7 = xT[ri[7] * BB + b];
  double best = 1e300;
  int bix = 0x7fffffff;
  float bestx = 0.0f;
  for (int i = 0; i < 512; ++i) {
    if ((double)eb[i] > best) break;
    int dj = ri[i];
    float xv;
    if (i < 8) {
      xv = (i == 0) ? x0 : (i == 1) ? x1 : (i == 2) ? x2 : (i == 3) ? x3
         : (i == 4) ? x4 : (i == 5) ? x5 : (i == 6) ? x6 : x7;
    } else {
      xv = xT[dj * BB + b];
    }
    double v = fmax((double)xv, rv[i]);
    if (v < best || (v == best && dj < bix)) { best = v; bix = dj; bestx = xv; }
  }
  float ox = fmaxf(bestx, wl[bix]);
  float ow = fmaxf(xT[iw * BB + b], wl[iw]);
  out[b * OO + o] = ox;
  out[BB * OO + b * OO + o] = ow;
}

// ===========================================================================
extern "C" void kernel_launch(void* const* d_in, const int* in_sizes, int n_in,
                              void* d_out, int out_size, void* d_ws,
                              size_t ws_size, hipStream_t stream) {
  const float* x = (const float*)d_in[0];  // (B,D)
  const float* w = (const float*)d_in[1];  // (D,O)
  const float* t = (const float*)d_in[2];  // (B,O)
  float* out = (float*)d_out;
  char* ws = (char*)d_ws;

  size_t off = 0;
  float* xT    = (float*)(ws + off);  off += (size_t)DD * BB * 4;       // 2 MB
  float* tT    = (float*)(ws + off);  off += (size_t)OO * BB * 4;       // 1 MB
  float* wT    = (float*)(ws + off);  off += (size_t)OO * DD * 4;       // .5 MB
  double* Sxp  = (double*)(ws + off); off += (size_t)DD * 8 * 8;        // 32 KB
  double* part = (double*)(ws + off); off += (size_t)OO * 8 * DD * 8;   // 8 MB
  float* sv_g  = (float*)(ws + off);  off += (size_t)OO * 512 * 4;
  int* si_g    = (int*)(ws + off);    off += (size_t)OO * 512 * 4;
  int* off_g   = (int*)(ws + off);    off += (size_t)OO * 513 * 4;
  double* P_g  = (double*)(ws + off); off += (size_t)OO * 513 * 8;
  int* Mx_g    = (int*)(ws + off);    off += (size_t)OO * 513 * 4;
  double* rv_g = (double*)(ws + off); off += (size_t)OO * 512 * 8;
  int* ri_g    = (int*)(ws + off);    off += (size_t)OO * 512 * 4;
  float* eb_g  = (float*)(ws + off);  off += (size_t)OO * 512 * 4;
  double* hdrW = (double*)(ws + off); off += (size_t)OO * 2 * 8;
  int* gmin_g  = (int*)(ws + off);    off += (size_t)OO * 4;

  kA<<<1424, 256, 0, stream>>>(x, w, t, xT, tT, wT, Sxp, part);
  kB<<<2 * OO, 256, 0, stream>>>(wT, Sxp, part, sv_g, si_g, off_g, P_g, Mx_g,
                                 rv_g, ri_g, eb_g, hdrW, gmin_g);
  kC<<<dim3(OO, BB / 256), 256, 0, stream>>>(xT, wT, tT, sv_g, si_g, off_g,
                                             P_g, Mx_g, rv_g, ri_g, eb_g,
                                             hdrW, gmin_g, out);
}